// Round 14
// baseline (31.293 us; speedup 1.0000x reference)
//
#include <hip/hip_runtime.h>
#include <math.h>

// Chamfer loss, B=8, C=3, M=N=4096, fp32 — MFMA, round 14.
//
// sq[m][n] = s2[m] + d2[n] - 2 s.d as a K=16 bf16 GEMM with hi/lo split:
//   A_m = [-2xh,-2xh,-2xl,-2xl | y.. | z.. | s2h,s2l,1,1]   (query rows)
//   B_n = [ xh,  xl,  xh,  xl  | y.. | z.. | 1,1,d2h,d2l]   (reference cols)
// C layout (m74/m101): col = lane&31, row = (reg&3) + 8*(reg>>2) + 4*(lane>>5)
//
// Round-14 = round-10 base (23.0 us known-good) + ONE change:
//   min3 merge — fwd = min(fwd, min(acc0, acc1)) -> one v_min3_f32 per
//   2 pairs (0.5 min-VALU/pair, was 1), halving the dominant VALU term;
//   also halves the butterfly epilogue (one accumulator, not E+O).
// r13 falsified the LDS-read theory (halving ds_read = no change), so the
// limiter is min-VALU issue. Live regs ~90 < 128 (r11/r12 spill lesson).
// Zero memsets (12B graph memset costs ~11 us), plain stores only.

constexpr int B = 8;
constexpr int M = 4096;   // == N

typedef __attribute__((ext_vector_type(8)))  short bf16x8;
typedef __attribute__((ext_vector_type(16))) float f32x16;

__device__ inline unsigned short bf16_of(float x) {   // round-to-nearest-even
    unsigned int u = __float_as_uint(x);
    u += 0x7FFFu + ((u >> 16) & 1u);
    return (unsigned short)(u >> 16);
}
__device__ inline float bf16_to_f(unsigned short h) {
    return __uint_as_float(((unsigned int)h) << 16);
}

// ws: part [2 cs][16 db][M] f32 @ 0   (512 KB) ; bsums [256] f32 @ 512 KB

// grid 1024 = (dir<<9 | b<<6 | rg<<1 | cs); 256 thr = 4 waves
// wave w: rows rg*128 + w*32 .. +32 ; cols cs*2048 .. +2048 (2 chunks of 1024)
__global__ __launch_bounds__(256, 4) void chamfer_main(
    const float* __restrict__ src,
    const float* __restrict__ dst,
    float* __restrict__ part)
{
    int bid = blockIdx.x;
    const int cs  = bid & 1;  bid >>= 1;
    const int rg  = bid & 31; bid >>= 5;
    const int b   = bid & 7;  bid >>= 3;
    const int dir = bid;      // 0: rows=src scan dst ; 1: rows=dst scan src

    const float* __restrict__ qry = dir ? dst : src;   // A-side (rows)
    const float* __restrict__ ref = dir ? src : dst;   // B-side (cols)

    const int tid  = threadIdx.x;
    const int wave = tid >> 6;
    const int l31  = tid & 31;
    const int hf   = (tid >> 5) & 1;    // k-group / row-half within wave

    __shared__ __align__(16) unsigned short bstage[2][1024][8];  // 32 KB

    // ---- augmented A fragment for this lane's row (constant across scan) ----
    bf16x8 afrag;
    {
        const int mrow = rg * 128 + wave * 32 + l31;
        const float* qb = qry + (size_t)b * 3 * M;
        const float x = qb[0 * M + mrow];
        const float y = qb[1 * M + mrow];
        const float z = qb[2 * M + mrow];
        const float s2 = x * x + y * y + z * z;
        const float xhf = bf16_to_f(bf16_of(x));
        const float yhf = bf16_to_f(bf16_of(y));
        const float zhf = bf16_to_f(bf16_of(z));
        // -2*hi exact (pow2 scale of a bf16 value)
        const unsigned short nxh = bf16_of(-2.0f * xhf), nxl = bf16_of(-2.0f * (x - xhf));
        const unsigned short nyh = bf16_of(-2.0f * yhf), nyl = bf16_of(-2.0f * (y - yhf));
        const unsigned short nzh = bf16_of(-2.0f * zhf), nzl = bf16_of(-2.0f * (z - zhf));
        const unsigned short s2h = bf16_of(s2);
        const unsigned short s2l = bf16_of(s2 - bf16_to_f(s2h));
        const unsigned short one = 0x3F80;
        bf16x8 alo, ahi;
        alo[0]=(short)nxh; alo[1]=(short)nxh; alo[2]=(short)nxl; alo[3]=(short)nxl;
        alo[4]=(short)nyh; alo[5]=(short)nyh; alo[6]=(short)nyl; alo[7]=(short)nyl;
        ahi[0]=(short)nzh; ahi[1]=(short)nzh; ahi[2]=(short)nzl; ahi[3]=(short)nzl;
        ahi[4]=(short)s2h; ahi[5]=(short)s2l; ahi[6]=(short)one; ahi[7]=(short)one;
        afrag = hf ? ahi : alo;
    }

    f32x16 fwd;
#pragma unroll
    for (int r = 0; r < 16; ++r) fwd[r] = 3.0e38f;

    const f32x16 zero = {};
    const float* rb = ref + (size_t)b * 3 * M + cs * 2048;

    for (int ch = 0; ch < 2; ++ch) {
        __syncthreads();   // previous chunk fully consumed before overwrite
        {
            // stage 1024 augmented B cols: 4 consecutive cols per thread,
            // float4 loads per coordinate row
            const int c0 = tid * 4;      // within-chunk col base
            const float4 vx = *reinterpret_cast<const float4*>(&rb[0 * M + ch * 1024 + c0]);
            const float4 vy = *reinterpret_cast<const float4*>(&rb[1 * M + ch * 1024 + c0]);
            const float4 vz = *reinterpret_cast<const float4*>(&rb[2 * M + ch * 1024 + c0]);
            const float xs[4] = {vx.x, vx.y, vx.z, vx.w};
            const float ys[4] = {vy.x, vy.y, vy.z, vy.w};
            const float zs[4] = {vz.x, vz.y, vz.z, vz.w};
#pragma unroll
            for (int k = 0; k < 4; ++k) {
                const float x = xs[k], y = ys[k], z = zs[k];
                const float d2 = x * x + y * y + z * z;
                const unsigned short xh = bf16_of(x), xl = bf16_of(x - bf16_to_f(xh));
                const unsigned short yh = bf16_of(y), yl = bf16_of(y - bf16_to_f(yh));
                const unsigned short zh = bf16_of(z), zl = bf16_of(z - bf16_to_f(zh));
                const unsigned short d2h = bf16_of(d2);
                const unsigned short d2l = bf16_of(d2 - bf16_to_f(d2h));
                const unsigned short one = 0x3F80;
                bf16x8 v0, v1;
                v0[0]=(short)xh; v0[1]=(short)xl; v0[2]=(short)xh; v0[3]=(short)xl;
                v0[4]=(short)yh; v0[5]=(short)yl; v0[6]=(short)yh; v0[7]=(short)yl;
                v1[0]=(short)zh; v1[1]=(short)zl; v1[2]=(short)zh; v1[3]=(short)zl;
                v1[4]=(short)one; v1[5]=(short)one; v1[6]=(short)d2h; v1[7]=(short)d2l;
                *reinterpret_cast<bf16x8*>(&bstage[0][c0 + k][0]) = v0;
                *reinterpret_cast<bf16x8*>(&bstage[1][c0 + k][0]) = v1;
            }
        }
        __syncthreads();

        // 32 tiles, 2 per step: 2 ds_read_b128 + 2 MFMA + 16 v_min3
#pragma unroll 4
        for (int i = 0; i < 16; ++i) {
            const bf16x8 bf0 = *reinterpret_cast<const bf16x8*>(&bstage[hf][i * 64 + l31][0]);
            const bf16x8 bf1 = *reinterpret_cast<const bf16x8*>(&bstage[hf][i * 64 + 32 + l31][0]);
            const f32x16 acc0 = __builtin_amdgcn_mfma_f32_32x32x16_bf16(afrag, bf0, zero, 0, 0, 0);
            const f32x16 acc1 = __builtin_amdgcn_mfma_f32_32x32x16_bf16(afrag, bf1, zero, 0, 0, 0);
#pragma unroll
            for (int r = 0; r < 16; ++r)
                fwd[r] = fminf(fwd[r], fminf(acc0[r], acc1[r]));   // v_min3_f32
        }
    }

    // butterfly min across the 32-lane col dimension (halves = distinct rows)
#pragma unroll
    for (int r = 0; r < 16; ++r) {
        float vv = fwd[r];
        vv = fminf(vv, __shfl_xor(vv, 1));
        vv = fminf(vv, __shfl_xor(vv, 2));
        vv = fminf(vv, __shfl_xor(vv, 4));
        vv = fminf(vv, __shfl_xor(vv, 8));
        vv = fminf(vv, __shfl_xor(vv, 16));
        fwd[r] = vv;
    }
    if (l31 == 0) {   // lanes 0 (row-half 0) and 32 (row-half 1): 16 row-mins each
        float* pf = part + ((size_t)cs * 16 + dir * 8 + b) * M
                  + rg * 128 + wave * 32 + hf * 4;
#pragma unroll
        for (int r = 0; r < 16; ++r)
            pf[(r & 3) + 8 * (r >> 2)] = fwd[r];
    }
}

// 256 blocks x 256 threads: min over the 2 col-splits, sqrt, block-sum -> bsums
__global__ __launch_bounds__(256) void chamfer_reduce(
    const float* __restrict__ part, float* __restrict__ bsums)
{
    const int idx = blockIdx.x * 256 + threadIdx.x;   // [0, 2*B*M)
    const int row = idx & (M - 1);
    const int db  = idx >> 12;                        // dir*8 + b

    const float* p = part + (size_t)db * M + row;
    const float v = fminf(p[0], p[(size_t)16 * M]);

    float s = sqrtf(fmaxf(v, 0.0f));
#pragma unroll
    for (int off = 32; off > 0; off >>= 1) s += __shfl_down(s, off);
    __shared__ float partial[4];
    if ((threadIdx.x & 63) == 0) partial[threadIdx.x >> 6] = s;
    __syncthreads();
    if (threadIdx.x == 0)
        bsums[blockIdx.x] = partial[0] + partial[1] + partial[2] + partial[3];
}

// 1 block: total, scale, plain-store out[0..2] (no memset needed anywhere)
__global__ __launch_bounds__(256) void chamfer_final(
    const float* __restrict__ bsums, float* __restrict__ out)
{
    float s = bsums[threadIdx.x];
#pragma unroll
    for (int off = 32; off > 0; off >>= 1) s += __shfl_down(s, off);
    __shared__ float partial[4];
    if ((threadIdx.x & 63) == 0) partial[threadIdx.x >> 6] = s;
    __syncthreads();
    if (threadIdx.x == 0) {
        const float tot = (partial[0] + partial[1] + partial[2] + partial[3])
                        * (1.0f / (float)(B * M));   // fwd /(B*M), bwd /(B*N), M==N
        out[0] = tot;
        out[1] = tot;
        out[2] = tot;
    }
}

extern "C" void kernel_launch(void* const* d_in, const int* in_sizes, int n_in,
                              void* d_out, int out_size, void* d_ws, size_t ws_size,
                              hipStream_t stream)
{
    const float* src = (const float*)d_in[0];   // [B,3,M]
    const float* dst = (const float*)d_in[1];   // [B,3,N]
    float* out = (float*)d_out;                 // 3 floats

    float* part  = (float*)d_ws;                          // 512 KB, fully written
    float* bsums = (float*)((char*)d_ws + (1u << 19));    // 256 floats, fully written

    chamfer_main  <<<1024, 256, 0, stream>>>(src, dst, part);
    chamfer_reduce<<<256, 256, 0, stream>>>(part, bsums);
    chamfer_final <<<1, 256, 0, stream>>>(bsums, out);
}

// Round 15
// 29.718 us; speedup vs baseline: 1.0530x; 1.0530x over previous
//
#include <hip/hip_runtime.h>
#include <math.h>

// Chamfer loss, B=8, C=3, M=N=4096, fp32 — MFMA, round 15.
//
// sq[m][n] = s2[m] + d2[n] - 2 s.d as a K=16 bf16 GEMM with hi/lo split:
//   A_m = [-2xh,-2xh,-2xl,-2xl | y.. | z.. | s2h,s2l,1,1]   (query rows)
//   B_n = [ xh,  xl,  xh,  xl  | y.. | z.. | 1,1,d2h,d2l]   (reference cols)
// C layout (m74/m101): col = lane&31, row = (reg&3) + 8*(reg>>2) + 4*(lane>>5)
//
// Round-15 model (fits r10-r14): per-CU LDS pipe is the limiter; clients were
// reads 5.1us + conflicted staging writes 5.1us (64*tid -> 8 of 32 banks) +
// shfl butterfly 6.4us (ds_bpermute IS the LDS pipe). Fix the last two:
//   - NO butterfly: all 64 lanes plain-store 16 per-lane partial row-mins to
//     part[cs][db][row][lane] (16 MB); reduce kernel finishes the min.
//   - staging swizzle: col c stored at LDS row ((c&7)<<7)|(c>>3) (bijective).
//     Writes: even lanes addr=16*(tid/2) -> banks sweep all 32, natural-min.
//     Reads: lane base ((l31&7)<<7)+(l31>>3), tile offset +8 rows/step ->
//     bank group (l31>>3)*4, 8 lanes/group * 4 words = natural-min. ✓
// KEEP: plain E/O v_min chains (v_min3 = +8us poison, r11/12/14), r10 grid
// (1024 blocks, 4 waves/SIMD, lb(256,4)), live regs ~90, zero memsets.

constexpr int B = 8;
constexpr int M = 4096;   // == N

typedef __attribute__((ext_vector_type(8)))  short bf16x8;
typedef __attribute__((ext_vector_type(16))) float f32x16;

__device__ inline unsigned short bf16_of(float x) {   // round-to-nearest-even
    unsigned int u = __float_as_uint(x);
    u += 0x7FFFu + ((u >> 16) & 1u);
    return (unsigned short)(u >> 16);
}
__device__ inline float bf16_to_f(unsigned short h) {
    return __uint_as_float(((unsigned int)h) << 16);
}

// ws: part [2 cs][16 db][4096 row][32 lane] f32 @ 0   (16 MB)
//     bsums [256] f32 @ 16 MB

// grid 1024 = (dir<<9 | b<<6 | rg<<1 | cs); 256 thr = 4 waves
// wave w: rows rg*128 + w*32 .. +32 ; cols cs*2048 .. +2048 (2 chunks of 1024)
__global__ __launch_bounds__(256, 4) void chamfer_main(
    const float* __restrict__ src,
    const float* __restrict__ dst,
    float* __restrict__ part)
{
    int bid = blockIdx.x;
    const int cs  = bid & 1;  bid >>= 1;
    const int rg  = bid & 31; bid >>= 5;
    const int b   = bid & 7;  bid >>= 3;
    const int dir = bid;      // 0: rows=src scan dst ; 1: rows=dst scan src

    const float* __restrict__ qry = dir ? dst : src;   // A-side (rows)
    const float* __restrict__ ref = dir ? src : dst;   // B-side (cols)

    const int tid  = threadIdx.x;
    const int wave = tid >> 6;
    const int l31  = tid & 31;
    const int hf   = (tid >> 5) & 1;    // k-group / row-half within wave

    __shared__ __align__(16) unsigned short bstage[2][1024][8];  // 32 KB

    // per-lane swizzled LDS read base (row units); tile i adds 8 rows (pair +4)
    const int lds_base = ((l31 & 7) << 7) + (l31 >> 3);

    // ---- augmented A fragment for this lane's row (constant across scan) ----
    bf16x8 afrag;
    {
        const int mrow = rg * 128 + wave * 32 + l31;
        const float* qb = qry + (size_t)b * 3 * M;
        const float x = qb[0 * M + mrow];
        const float y = qb[1 * M + mrow];
        const float z = qb[2 * M + mrow];
        const float s2 = x * x + y * y + z * z;
        const float xhf = bf16_to_f(bf16_of(x));
        const float yhf = bf16_to_f(bf16_of(y));
        const float zhf = bf16_to_f(bf16_of(z));
        // -2*hi exact (pow2 scale of a bf16 value)
        const unsigned short nxh = bf16_of(-2.0f * xhf), nxl = bf16_of(-2.0f * (x - xhf));
        const unsigned short nyh = bf16_of(-2.0f * yhf), nyl = bf16_of(-2.0f * (y - yhf));
        const unsigned short nzh = bf16_of(-2.0f * zhf), nzl = bf16_of(-2.0f * (z - zhf));
        const unsigned short s2h = bf16_of(s2);
        const unsigned short s2l = bf16_of(s2 - bf16_to_f(s2h));
        const unsigned short one = 0x3F80;
        bf16x8 alo, ahi;
        alo[0]=(short)nxh; alo[1]=(short)nxh; alo[2]=(short)nxl; alo[3]=(short)nxl;
        alo[4]=(short)nyh; alo[5]=(short)nyh; alo[6]=(short)nyl; alo[7]=(short)nyl;
        ahi[0]=(short)nzh; ahi[1]=(short)nzh; ahi[2]=(short)nzl; ahi[3]=(short)nzl;
        ahi[4]=(short)s2h; ahi[5]=(short)s2l; ahi[6]=(short)one; ahi[7]=(short)one;
        afrag = hf ? ahi : alo;
    }

    f32x16 fwdE, fwdO;
#pragma unroll
    for (int r = 0; r < 16; ++r) { fwdE[r] = 3.0e38f; fwdO[r] = 3.0e38f; }

    const f32x16 zero = {};
    const float* rb = ref + (size_t)b * 3 * M + cs * 2048;

    for (int ch = 0; ch < 2; ++ch) {
        __syncthreads();   // previous chunk fully consumed before overwrite
        {
            // stage 1024 augmented B cols, 4 per thread, swizzled rows
            const int c0 = tid * 4;
            const float4 vx = *reinterpret_cast<const float4*>(&rb[0 * M + ch * 1024 + c0]);
            const float4 vy = *reinterpret_cast<const float4*>(&rb[1 * M + ch * 1024 + c0]);
            const float4 vz = *reinterpret_cast<const float4*>(&rb[2 * M + ch * 1024 + c0]);
            const float xs[4] = {vx.x, vx.y, vx.z, vx.w};
            const float ys[4] = {vy.x, vy.y, vy.z, vy.w};
            const float zs[4] = {vz.x, vz.y, vz.z, vz.w};
#pragma unroll
            for (int k = 0; k < 4; ++k) {
                const float x = xs[k], y = ys[k], z = zs[k];
                const float d2 = x * x + y * y + z * z;
                const unsigned short xh = bf16_of(x), xl = bf16_of(x - bf16_to_f(xh));
                const unsigned short yh = bf16_of(y), yl = bf16_of(y - bf16_to_f(yh));
                const unsigned short zh = bf16_of(z), zl = bf16_of(z - bf16_to_f(zh));
                const unsigned short d2h = bf16_of(d2);
                const unsigned short d2l = bf16_of(d2 - bf16_to_f(d2h));
                const unsigned short one = 0x3F80;
                bf16x8 v0, v1;
                v0[0]=(short)xh; v0[1]=(short)xl; v0[2]=(short)xh; v0[3]=(short)xl;
                v0[4]=(short)yh; v0[5]=(short)yl; v0[6]=(short)yh; v0[7]=(short)yl;
                v1[0]=(short)zh; v1[1]=(short)zl; v1[2]=(short)zh; v1[3]=(short)zl;
                v1[4]=(short)one; v1[5]=(short)one; v1[6]=(short)d2h; v1[7]=(short)d2l;
                const int c = c0 + k;
                const int swz = ((c & 7) << 7) + (c >> 3);   // bijective bank-spread
                *reinterpret_cast<bf16x8*>(&bstage[0][swz][0]) = v0;
                *reinterpret_cast<bf16x8*>(&bstage[1][swz][0]) = v1;
            }
        }
        __syncthreads();

        // 32 tiles, 2 per step: 2 ds_read_b128 + 2 MFMA + 32 v_min (E/O chains)
#pragma unroll 4
        for (int i = 0; i < 16; ++i) {
            // col i*64+l31 -> swz row = lds_base + i*8 ; col +32 -> +4 rows
            const bf16x8 bf0 = *reinterpret_cast<const bf16x8*>(&bstage[hf][lds_base + i * 8][0]);
            const bf16x8 bf1 = *reinterpret_cast<const bf16x8*>(&bstage[hf][lds_base + i * 8 + 4][0]);
            const f32x16 acc0 = __builtin_amdgcn_mfma_f32_32x32x16_bf16(afrag, bf0, zero, 0, 0, 0);
            const f32x16 acc1 = __builtin_amdgcn_mfma_f32_32x32x16_bf16(afrag, bf1, zero, 0, 0, 0);
#pragma unroll
            for (int r = 0; r < 16; ++r) {
                fwdE[r] = fminf(fwdE[r], acc0[r]);   // plain v_min — NO min3
                fwdO[r] = fminf(fwdO[r], acc1[r]);
            }
        }
    }

    // NO butterfly: every lane stores its 16 per-lane partials (col-residue l31)
    // part[((cs*16+db)*4096 + row)*32 + l31], row = rg*128+wave*32+(r&3)+8*(r>>2)+4*hf
    {
        float* pf = part + (((size_t)cs * 16 + (size_t)dir * 8 + b) * 4096
                            + rg * 128 + wave * 32 + hf * 4) * 32 + l31;
#pragma unroll
        for (int r = 0; r < 16; ++r) {
            const float v = fminf(fwdE[r], fwdO[r]);
            pf[(size_t)((r & 3) + 8 * (r >> 2)) * 32] = v;
        }
    }
}

// 256 blocks x 256 threads: one thread per (db,row): min over 2 cs x 32 lanes,
// sqrt, block-sum -> bsums
__global__ __launch_bounds__(256) void chamfer_reduce(
    const float* __restrict__ part, float* __restrict__ bsums)
{
    const int idx = blockIdx.x * 256 + threadIdx.x;   // [0, 2*B*M)
    const int row = idx & (M - 1);
    const int db  = idx >> 12;                        // dir*8 + b

    const float4* p0 = reinterpret_cast<const float4*>(
        part + ((size_t)(0 * 16 + db) * 4096 + row) * 32);
    const float4* p1 = reinterpret_cast<const float4*>(
        part + ((size_t)(1 * 16 + db) * 4096 + row) * 32);

    float m0 = 3.0e38f, m1 = 3.0e38f, m2 = 3.0e38f, m3 = 3.0e38f;
#pragma unroll
    for (int j = 0; j < 8; ++j) {
        const float4 a = p0[j];
        const float4 b = p1[j];
        m0 = fminf(m0, fminf(a.x, b.x));
        m1 = fminf(m1, fminf(a.y, b.y));
        m2 = fminf(m2, fminf(a.z, b.z));
        m3 = fminf(m3, fminf(a.w, b.w));
    }
    const float v = fminf(fminf(m0, m1), fminf(m2, m3));

    float s = sqrtf(fmaxf(v, 0.0f));
#pragma unroll
    for (int off = 32; off > 0; off >>= 1) s += __shfl_down(s, off);
    __shared__ float partial[4];
    if ((threadIdx.x & 63) == 0) partial[threadIdx.x >> 6] = s;
    __syncthreads();
    if (threadIdx.x == 0)
        bsums[blockIdx.x] = partial[0] + partial[1] + partial[2] + partial[3];
}

// 1 block: total, scale, plain-store out[0..2] (no memset needed anywhere)
__global__ __launch_bounds__(256) void chamfer_final(
    const float* __restrict__ bsums, float* __restrict__ out)
{
    float s = bsums[threadIdx.x];
#pragma unroll
    for (int off = 32; off > 0; off >>= 1) s += __shfl_down(s, off);
    __shared__ float partial[4];
    if ((threadIdx.x & 63) == 0) partial[threadIdx.x >> 6] = s;
    __syncthreads();
    if (threadIdx.x == 0) {
        const float tot = (partial[0] + partial[1] + partial[2] + partial[3])
                        * (1.0f / (float)(B * M));   // fwd /(B*M), bwd /(B*N), M==N
        out[0] = tot;
        out[1] = tot;
        out[2] = tot;
    }
}

extern "C" void kernel_launch(void* const* d_in, const int* in_sizes, int n_in,
                              void* d_out, int out_size, void* d_ws, size_t ws_size,
                              hipStream_t stream)
{
    const float* src = (const float*)d_in[0];   // [B,3,M]
    const float* dst = (const float*)d_in[1];   // [B,3,N]
    float* out = (float*)d_out;                 // 3 floats

    float* part  = (float*)d_ws;                          // 16 MB, fully written
    float* bsums = (float*)((char*)d_ws + (16u << 20));   // 256 floats, fully written

    chamfer_main  <<<1024, 256, 0, stream>>>(src, dst, part);
    chamfer_reduce<<<256, 256, 0, stream>>>(part, bsums);
    chamfer_final <<<1, 256, 0, stream>>>(bsums, out);
}

// Round 16
// 22.025 us; speedup vs baseline: 1.4208x; 1.3493x over previous
//
#include <hip/hip_runtime.h>
#include <math.h>

// Chamfer loss, B=8, C=3, M=N=4096, fp32 — MFMA, round 16.
//
// sq[m][n] = s2[m] + d2[n] - 2 s.d as a K=16 bf16 GEMM with hi/lo split:
//   A_m = [-2xh,-2xh,-2xl,-2xl | y.. | z.. | s2h,s2l,1,1]   (query rows)
//   B_n = [ xh,  xl,  xh,  xl  | y.. | z.. | 1,1,d2h,d2l]   (reference cols)
// C layout (m74/m101): col = lane&31, row = (reg&3) + 8*(reg>>2) + 4*(lane>>5)
//
// Round-16 = round-10 base (23.0 us best) + ONE change: XOR bank swizzle
// row' = c ^ ((c>>3)&7) on the B-stage. Ledger that fits r10-r15:
//   per-CU LDS: reads 5.1us (natural b128 = minimum) + WRITES ~5.1us
//   (r10 pattern 64*tid: banks {4k..4k+3}+{+16} only -> 4x conflicted)
//   + butterfly 3.1us + VALU 4.9us => main ~16us.
// This swizzle is conflict-free BOTH ways (bank math verified):
//   writes: group = (4(L&1)|k) ^ ((L>>1)&7) covers all 8 groups, 8 dw/bank.
//   reads:  XOR operand is lane-only -> addr = i*1024B + per-lane const;
//           each 8-lane group covers all 8 bank groups = natural minimum.
// KEEP: plain E/O v_min chains (min3 = +8us poison, r14), lb(256,4), 1024
// blocks, 32KB LDS, butterfly epilogue, 512KB partials, zero memsets.

constexpr int B = 8;
constexpr int M = 4096;   // == N

typedef __attribute__((ext_vector_type(8)))  short bf16x8;
typedef __attribute__((ext_vector_type(16))) float f32x16;

__device__ inline unsigned short bf16_of(float x) {   // round-to-nearest-even
    unsigned int u = __float_as_uint(x);
    u += 0x7FFFu + ((u >> 16) & 1u);
    return (unsigned short)(u >> 16);
}
__device__ inline float bf16_to_f(unsigned short h) {
    return __uint_as_float(((unsigned int)h) << 16);
}

// ws: part [2 cs][16 db][M] f32 @ 0   (512 KB) ; bsums [256] f32 @ 512 KB

// grid 1024 = (dir<<9 | b<<6 | rg<<1 | cs); 256 thr = 4 waves
// wave w: rows rg*128 + w*32 .. +32 ; cols cs*2048 .. +2048 (2 chunks of 1024)
__global__ __launch_bounds__(256, 4) void chamfer_main(
    const float* __restrict__ src,
    const float* __restrict__ dst,
    float* __restrict__ part)
{
    int bid = blockIdx.x;
    const int cs  = bid & 1;  bid >>= 1;
    const int rg  = bid & 31; bid >>= 5;
    const int b   = bid & 7;  bid >>= 3;
    const int dir = bid;      // 0: rows=src scan dst ; 1: rows=dst scan src

    const float* __restrict__ qry = dir ? dst : src;   // A-side (rows)
    const float* __restrict__ ref = dir ? src : dst;   // B-side (cols)

    const int tid  = threadIdx.x;
    const int wave = tid >> 6;
    const int l31  = tid & 31;
    const int hf   = (tid >> 5) & 1;    // k-group / row-half within wave

    __shared__ __align__(16) unsigned short bstage[2][1024][8];  // 32 KB

    // per-lane swizzled read rows: col i*64+l31 -> i*64 + sA ; +32 -> i*64 + sB
    const int sA = l31 ^ (l31 >> 3);
    const int sB = 32 + (l31 ^ (4 | (l31 >> 3)));

    // ---- augmented A fragment for this lane's row (constant across scan) ----
    bf16x8 afrag;
    {
        const int mrow = rg * 128 + wave * 32 + l31;
        const float* qb = qry + (size_t)b * 3 * M;
        const float x = qb[0 * M + mrow];
        const float y = qb[1 * M + mrow];
        const float z = qb[2 * M + mrow];
        const float s2 = x * x + y * y + z * z;
        const float xhf = bf16_to_f(bf16_of(x));
        const float yhf = bf16_to_f(bf16_of(y));
        const float zhf = bf16_to_f(bf16_of(z));
        // -2*hi exact (pow2 scale of a bf16 value)
        const unsigned short nxh = bf16_of(-2.0f * xhf), nxl = bf16_of(-2.0f * (x - xhf));
        const unsigned short nyh = bf16_of(-2.0f * yhf), nyl = bf16_of(-2.0f * (y - yhf));
        const unsigned short nzh = bf16_of(-2.0f * zhf), nzl = bf16_of(-2.0f * (z - zhf));
        const unsigned short s2h = bf16_of(s2);
        const unsigned short s2l = bf16_of(s2 - bf16_to_f(s2h));
        const unsigned short one = 0x3F80;
        bf16x8 alo, ahi;
        alo[0]=(short)nxh; alo[1]=(short)nxh; alo[2]=(short)nxl; alo[3]=(short)nxl;
        alo[4]=(short)nyh; alo[5]=(short)nyh; alo[6]=(short)nyl; alo[7]=(short)nyl;
        ahi[0]=(short)nzh; ahi[1]=(short)nzh; ahi[2]=(short)nzl; ahi[3]=(short)nzl;
        ahi[4]=(short)s2h; ahi[5]=(short)s2l; ahi[6]=(short)one; ahi[7]=(short)one;
        afrag = hf ? ahi : alo;
    }

    f32x16 fwdE, fwdO;
#pragma unroll
    for (int r = 0; r < 16; ++r) { fwdE[r] = 3.0e38f; fwdO[r] = 3.0e38f; }

    const f32x16 zero = {};
    const float* rb = ref + (size_t)b * 3 * M + cs * 2048;

    for (int ch = 0; ch < 2; ++ch) {
        __syncthreads();   // previous chunk fully consumed before overwrite
        {
            // stage 1024 augmented B cols: 4 consecutive cols per thread,
            // float4 loads per coordinate row, XOR-swizzled LDS rows
            const int c0 = tid * 4;      // within-chunk col base
            const float4 vx = *reinterpret_cast<const float4*>(&rb[0 * M + ch * 1024 + c0]);
            const float4 vy = *reinterpret_cast<const float4*>(&rb[1 * M + ch * 1024 + c0]);
            const float4 vz = *reinterpret_cast<const float4*>(&rb[2 * M + ch * 1024 + c0]);
            const float xs[4] = {vx.x, vx.y, vx.z, vx.w};
            const float ys[4] = {vy.x, vy.y, vy.z, vy.w};
            const float zs[4] = {vz.x, vz.y, vz.z, vz.w};
#pragma unroll
            for (int k = 0; k < 4; ++k) {
                const float x = xs[k], y = ys[k], z = zs[k];
                const float d2 = x * x + y * y + z * z;
                const unsigned short xh = bf16_of(x), xl = bf16_of(x - bf16_to_f(xh));
                const unsigned short yh = bf16_of(y), yl = bf16_of(y - bf16_to_f(yh));
                const unsigned short zh = bf16_of(z), zl = bf16_of(z - bf16_to_f(zh));
                const unsigned short d2h = bf16_of(d2);
                const unsigned short d2l = bf16_of(d2 - bf16_to_f(d2h));
                const unsigned short one = 0x3F80;
                bf16x8 v0, v1;
                v0[0]=(short)xh; v0[1]=(short)xl; v0[2]=(short)xh; v0[3]=(short)xl;
                v0[4]=(short)yh; v0[5]=(short)yl; v0[6]=(short)yh; v0[7]=(short)yl;
                v1[0]=(short)zh; v1[1]=(short)zl; v1[2]=(short)zh; v1[3]=(short)zl;
                v1[4]=(short)one; v1[5]=(short)one; v1[6]=(short)d2h; v1[7]=(short)d2l;
                const int c = c0 + k;
                const int swz = c ^ ((c >> 3) & 7);   // bijective, both-side min
                *reinterpret_cast<bf16x8*>(&bstage[0][swz][0]) = v0;
                *reinterpret_cast<bf16x8*>(&bstage[1][swz][0]) = v1;
            }
        }
        __syncthreads();

        // 32 tiles, 2 per step: 2 ds_read_b128 + 2 MFMA + 32 v_min (E/O chains)
#pragma unroll 4
        for (int i = 0; i < 16; ++i) {
            const bf16x8 bf0 = *reinterpret_cast<const bf16x8*>(&bstage[hf][i * 64 + sA][0]);
            const bf16x8 bf1 = *reinterpret_cast<const bf16x8*>(&bstage[hf][i * 64 + sB][0]);
            const f32x16 acc0 = __builtin_amdgcn_mfma_f32_32x32x16_bf16(afrag, bf0, zero, 0, 0, 0);
            const f32x16 acc1 = __builtin_amdgcn_mfma_f32_32x32x16_bf16(afrag, bf1, zero, 0, 0, 0);
#pragma unroll
            for (int r = 0; r < 16; ++r) {
                fwdE[r] = fminf(fwdE[r], acc0[r]);   // plain v_min — NO min3
                fwdO[r] = fminf(fwdO[r], acc1[r]);
            }
        }
    }

    f32x16 fwd;
#pragma unroll
    for (int r = 0; r < 16; ++r) fwd[r] = fminf(fwdE[r], fwdO[r]);

    // butterfly min across the 32-lane col dimension (halves = distinct rows)
#pragma unroll
    for (int r = 0; r < 16; ++r) {
        float vv = fwd[r];
        vv = fminf(vv, __shfl_xor(vv, 1));
        vv = fminf(vv, __shfl_xor(vv, 2));
        vv = fminf(vv, __shfl_xor(vv, 4));
        vv = fminf(vv, __shfl_xor(vv, 8));
        vv = fminf(vv, __shfl_xor(vv, 16));
        fwd[r] = vv;
    }
    if (l31 == 0) {   // lanes 0 (row-half 0) and 32 (row-half 1): 16 row-mins each
        float* pf = part + ((size_t)cs * 16 + dir * 8 + b) * M
                  + rg * 128 + wave * 32 + hf * 4;
#pragma unroll
        for (int r = 0; r < 16; ++r)
            pf[(r & 3) + 8 * (r >> 2)] = fwd[r];
    }
}

// 256 blocks x 256 threads: min over the 2 col-splits, sqrt, block-sum -> bsums
__global__ __launch_bounds__(256) void chamfer_reduce(
    const float* __restrict__ part, float* __restrict__ bsums)
{
    const int idx = blockIdx.x * 256 + threadIdx.x;   // [0, 2*B*M)
    const int row = idx & (M - 1);
    const int db  = idx >> 12;                        // dir*8 + b

    const float* p = part + (size_t)db * M + row;
    const float v = fminf(p[0], p[(size_t)16 * M]);

    float s = sqrtf(fmaxf(v, 0.0f));
#pragma unroll
    for (int off = 32; off > 0; off >>= 1) s += __shfl_down(s, off);
    __shared__ float partial[4];
    if ((threadIdx.x & 63) == 0) partial[threadIdx.x >> 6] = s;
    __syncthreads();
    if (threadIdx.x == 0)
        bsums[blockIdx.x] = partial[0] + partial[1] + partial[2] + partial[3];
}

// 1 block: total, scale, plain-store out[0..2] (no memset needed anywhere)
__global__ __launch_bounds__(256) void chamfer_final(
    const float* __restrict__ bsums, float* __restrict__ out)
{
    float s = bsums[threadIdx.x];
#pragma unroll
    for (int off = 32; off > 0; off >>= 1) s += __shfl_down(s, off);
    __shared__ float partial[4];
    if ((threadIdx.x & 63) == 0) partial[threadIdx.x >> 6] = s;
    __syncthreads();
    if (threadIdx.x == 0) {
        const float tot = (partial[0] + partial[1] + partial[2] + partial[3])
                        * (1.0f / (float)(B * M));   // fwd /(B*M), bwd /(B*N), M==N
        out[0] = tot;
        out[1] = tot;
        out[2] = tot;
    }
}

extern "C" void kernel_launch(void* const* d_in, const int* in_sizes, int n_in,
                              void* d_out, int out_size, void* d_ws, size_t ws_size,
                              hipStream_t stream)
{
    const float* src = (const float*)d_in[0];   // [B,3,M]
    const float* dst = (const float*)d_in[1];   // [B,3,N]
    float* out = (float*)d_out;                 // 3 floats

    float* part  = (float*)d_ws;                          // 512 KB, fully written
    float* bsums = (float*)((char*)d_ws + (1u << 19));    // 256 floats, fully written

    chamfer_main  <<<1024, 256, 0, stream>>>(src, dst, part);
    chamfer_reduce<<<256, 256, 0, stream>>>(part, bsums);
    chamfer_final <<<1, 256, 0, stream>>>(bsums, out);
}